// Round 1
// baseline (310.862 us; speedup 1.0000x reference)
//
#include <hip/hip_runtime.h>
#include <hip/hip_bf16.h>

#define NS 25      // n_support
#define NW 5       // n_way
#define D  1024
#define NQ 75      // n_query
#define CHUNK 128
#define SPAD 132               // chunk row stride (floats); 132*4=528B = 33*16B -> float4-aligned, 33%32=1 -> spread banks
#define NCHUNK (D / CHUNK)     // 8
#define WROW 1056              // W row stride: 1024 + 8 pads of 4 floats (one per 128-k block)

// ---------------- Kernel 1: K = S S^T + I, Gauss-Jordan solve, write A = K^{-1} Y ----------------
__global__ __launch_bounds__(256) void k_solve(const float* __restrict__ S,
                                               const int* __restrict__ labels,
                                               float* __restrict__ A_ws) {
    const int b = blockIdx.x;
    const int t = threadIdx.x;

    __shared__ float s_chunk[NS * SPAD];     // 13.2 KB
    __shared__ float kpart[8 * NS * NS];     // 20 KB   (8 k-subslice partials)
    __shared__ float M[NS * 33];             // augmented [K | Y], padded stride 33
    __shared__ float prow[32];
    __shared__ float pcol[NS];

    const float* Sb = S + (size_t)b * NS * D;

    // K accumulation: 25 tiles of 5x5 over (i,j), 8 k-subslices -> 200 worker threads
    float acc[5][5];
    const int tile = t >> 3;          // 0..24 (for t<200)
    const int sk   = t & 7;           // 0..7
    const int i0 = (tile / 5) * 5;
    const int j0 = (tile % 5) * 5;
    if (t < 200) {
#pragma unroll
        for (int a = 0; a < 5; ++a)
#pragma unroll
            for (int c = 0; c < 5; ++c) acc[a][c] = 0.f;
    }

    for (int ch = 0; ch < NCHUNK; ++ch) {
        // stage chunk: 25 rows x 128 floats = 800 float4, coalesced
        for (int g = t; g < NS * 32; g += 256) {
            const int row = g >> 5;
            const int c4  = g & 31;
            float4 v = *reinterpret_cast<const float4*>(Sb + row * D + ch * CHUNK + c4 * 4);
            *reinterpret_cast<float4*>(&s_chunk[row * SPAD + c4 * 4]) = v;
        }
        __syncthreads();
        if (t < 200) {
#pragma unroll
            for (int ii = 0; ii < 4; ++ii) {
                const int kl = sk * 16 + ii * 4;
                float4 si[5], sj[5];
#pragma unroll
                for (int a = 0; a < 5; ++a)
                    si[a] = *reinterpret_cast<const float4*>(&s_chunk[(i0 + a) * SPAD + kl]);
#pragma unroll
                for (int a = 0; a < 5; ++a)
                    sj[a] = *reinterpret_cast<const float4*>(&s_chunk[(j0 + a) * SPAD + kl]);
#pragma unroll
                for (int a = 0; a < 5; ++a)
#pragma unroll
                    for (int c = 0; c < 5; ++c)
                        acc[a][c] += si[a].x * sj[c].x + si[a].y * sj[c].y +
                                     si[a].z * sj[c].z + si[a].w * sj[c].w;
            }
        }
        __syncthreads();
    }

    if (t < 200) {
#pragma unroll
        for (int a = 0; a < 5; ++a)
#pragma unroll
            for (int c = 0; c < 5; ++c)
                kpart[sk * NS * NS + (i0 + a) * NS + (j0 + c)] = acc[a][c];
    }
    __syncthreads();

    // reduce partials -> M[:, 0:25] (+ lambda I)
    for (int item = t; item < NS * NS; item += 256) {
        const int i = item / NS, j = item % NS;
        float s = 0.f;
#pragma unroll
        for (int p = 0; p < 8; ++p) s += kpart[p * NS * NS + item];
        if (i == j) s += 1.0f;   // LAMBDA_REG
        M[i * 33 + j] = s;
    }
    // Y one-hot -> M[:, 25:30]
    if (t < NS * NW) {
        const int i = t / NW, c = t % NW;
        const int lab = labels[b * NS + i];
        M[i * 33 + NS + c] = (lab == c) ? 1.f : 0.f;
    }
    __syncthreads();

    // Gauss-Jordan (no pivoting; K is SPD, strongly diag-dominant here)
    for (int p = 0; p < NS; ++p) {
        if (t < 30) prow[t] = M[p * 33 + t];
        if (t >= 32 && t < 32 + NS) pcol[t - 32] = M[(t - 32) * 33 + p];
        __syncthreads();
        const float finv = 1.0f / prow[p];
        for (int item = t; item < NS * 30; item += 256) {
            const int r = item / 30, c = item % 30;
            if (r == p) M[r * 33 + c] = prow[c] * finv;
            else        M[r * 33 + c] = M[r * 33 + c] - pcol[r] * finv * prow[c];
        }
        __syncthreads();
    }

    // write A (25x5)
    if (t < NS * NW) {
        A_ws[(size_t)b * NS * NW + t] = M[(t / NW) * 33 + NS + (t % NW)];
    }
}

// ---------------- Kernel 2: W = S^T A (in LDS), logits = scale * (Q W) ----------------
__global__ __launch_bounds__(640) void k_logits(const float* __restrict__ Q,
                                                const float* __restrict__ S,
                                                const float* __restrict__ A_ws,
                                                const float* __restrict__ scale,
                                                float* __restrict__ out) {
    const int b = blockIdx.x;
    const int t = threadIdx.x;

    __shared__ float s_chunk[NS * SPAD];     // 13.2 KB
    __shared__ float Wl[NW * WROW];          // 21.1 KB, swizzled: c*1056 + k + 4*(k>>7)
    __shared__ float A_s[NS * NW];           // 125
    __shared__ float part[NQ * NW * 8];      // 12 KB

    const float* Sb = S + (size_t)b * NS * D;
    const float* Qb = Q + (size_t)b * NQ * D;

    if (t < NS * NW) A_s[t] = A_ws[(size_t)b * NS * NW + t];
    __syncthreads();

    // build W[c][k] = sum_j A[j][c] * S[j][k], chunk by chunk
    for (int ch = 0; ch < NCHUNK; ++ch) {
        for (int g = t; g < NS * 32; g += 640) {
            const int row = g >> 5;
            const int c4  = g & 31;
            *reinterpret_cast<float4*>(&s_chunk[row * SPAD + c4 * 4]) =
                *reinterpret_cast<const float4*>(Sb + row * D + ch * CHUNK + c4 * 4);
        }
        __syncthreads();
        {
            const int c  = t / CHUNK;   // 0..4
            const int kl = t % CHUNK;   // 0..127
            float sum = 0.f;
#pragma unroll
            for (int j = 0; j < NS; ++j) sum += A_s[j * NW + c] * s_chunk[j * SPAD + kl];
            const int k = ch * CHUNK + kl;
            Wl[c * WROW + k + 4 * (k >> 7)] = sum;
        }
        __syncthreads();
    }

    // stream Q: thread = (q, ks), q-row dot with 5 W columns over k-slice of 128
    float acc[NW] = {0.f, 0.f, 0.f, 0.f, 0.f};
    const int q  = t >> 3;   // 0..79
    const int ks = t & 7;    // 0..7
    if (q < NQ) {
        const float* qrow = Qb + q * D + ks * CHUNK;
        const int wbase = ks * CHUNK + 4 * ks;   // k + 4*(k>>7) with k = ks*128
#pragma unroll 4
        for (int i = 0; i < 32; ++i) {
            const float4 qv = *reinterpret_cast<const float4*>(qrow + i * 4);
            const int wi = wbase + i * 4;
#pragma unroll
            for (int c = 0; c < NW; ++c) {
                const float4 wv = *reinterpret_cast<const float4*>(&Wl[c * WROW + wi]);
                acc[c] += qv.x * wv.x + qv.y * wv.y + qv.z * wv.z + qv.w * wv.w;
            }
        }
#pragma unroll
        for (int c = 0; c < NW; ++c) part[(q * NW + c) * 8 + ks] = acc[c];
    }
    __syncthreads();

    if (t < NQ * NW) {
        float s = 0.f;
#pragma unroll
        for (int p = 0; p < 8; ++p) s += part[t * 8 + p];
        out[(size_t)b * NQ * NW + t] = s * scale[0];
    }
}

extern "C" void kernel_launch(void* const* d_in, const int* in_sizes, int n_in,
                              void* d_out, int out_size, void* d_ws, size_t ws_size,
                              hipStream_t stream) {
    const float* Q      = (const float*)d_in[0];
    const float* S      = (const float*)d_in[1];
    const int*   labels = (const int*)d_in[2];
    const float* scale  = (const float*)d_in[3];
    const int B = in_sizes[1] / (NS * D);   // 512

    float* A_ws = (float*)d_ws;             // B*25*5 floats = 256 KB

    k_solve<<<B, 256, 0, stream>>>(S, labels, A_ws);
    k_logits<<<B, 640, 0, stream>>>(Q, S, A_ws, scale, (float*)d_out);
}

// Round 3
// 303.113 us; speedup vs baseline: 1.0256x; 1.0256x over previous
//
#include <hip/hip_runtime.h>
#include <hip/hip_bf16.h>

#define NS 25      // n_support
#define NW 5       // n_way
#define D  1024
#define NQ 75      // n_query
#define SPAD 132   // k_solve chunk row stride (floats): 132%32=4 -> banks spread per row

// async 16B global->LDS DMA. LDS dest semantics: wave-uniform base + lane*16.
__device__ __forceinline__ void async_ld16(const float* gsrc, float* ldst) {
    __builtin_amdgcn_global_load_lds(
        (const __attribute__((address_space(1))) void*)gsrc,
        (__attribute__((address_space(3))) void*)ldst, 16, 0, 0);
}

// ---------------- Kernel 1: K = S S^T + I, Gauss-Jordan, A = K^{-1} Y ----------------
__global__ __launch_bounds__(256) void k_solve(const float* __restrict__ S,
                                               const int* __restrict__ labels,
                                               float* __restrict__ A_ws) {
    const int b = blockIdx.x;
    const int t = threadIdx.x;

    __shared__ float s_chunk[2][NS * SPAD];   // 2 x 13.2 KB
    __shared__ float kpart[8][NS * NS];       // 20 KB
    __shared__ float M[NS * 33];
    __shared__ float prow[32];
    __shared__ float pcol[NS];

    const float4* Sb4 = (const float4*)(S + (size_t)b * NS * D);

    // T14 reg-staged double buffer: 800 float4 per 128-float chunk, 256 threads
    float4 r0, r1, r2, r3 = make_float4(0.f, 0.f, 0.f, 0.f);
    auto LOADC = [&](int ch) {
        r0 = Sb4[((t      ) >> 5) * 256 + ch * 32 + ((t      ) & 31)];
        r1 = Sb4[((t + 256) >> 5) * 256 + ch * 32 + ((t + 256) & 31)];
        r2 = Sb4[((t + 512) >> 5) * 256 + ch * 32 + ((t + 512) & 31)];
        if (t < 32) r3 = Sb4[((t + 768) >> 5) * 256 + ch * 32 + ((t + 768) & 31)];
    };
    auto WRITEC = [&](int bb) {
        *(float4*)&s_chunk[bb][((t      ) >> 5) * SPAD + ((t      ) & 31) * 4] = r0;
        *(float4*)&s_chunk[bb][((t + 256) >> 5) * SPAD + ((t + 256) & 31) * 4] = r1;
        *(float4*)&s_chunk[bb][((t + 512) >> 5) * SPAD + ((t + 512) & 31) * 4] = r2;
        if (t < 32)
            *(float4*)&s_chunk[bb][((t + 768) >> 5) * SPAD + ((t + 768) & 31) * 4] = r3;
    };

    // symmetric gram: 15 upper tiles (ti<=tj) x 8 k-slices = 120 workers
    const int tile = t >> 3;          // 0..14 valid for t<120
    const int sk   = t & 7;
    const int ti = (tile < 5) ? 0 : (tile < 9) ? 1 : (tile < 12) ? 2 : (tile < 14) ? 3 : 4;
    const int tbase = (ti == 0) ? 0 : (ti == 1) ? 5 : (ti == 2) ? 9 : (ti == 3) ? 12 : 14;
    const int tj = ti + (tile - tbase);
    const int i0 = ti * 5, j0 = tj * 5;
    float acc[5][5] = {};

    LOADC(0); WRITEC(0); LOADC(1);
    asm volatile("s_waitcnt lgkmcnt(0)" ::: "memory");
    __builtin_amdgcn_s_barrier();

    for (int ch = 0; ch < 8; ++ch) {
        if (t < 120) {
            const float* sc_ = s_chunk[ch & 1];
#pragma unroll
            for (int ii = 0; ii < 4; ++ii) {
                const int kl = sk * 4 + ii * 32;   // 8 distinct bank groups across sk
                float4 si[5], sj[5];
#pragma unroll
                for (int a = 0; a < 5; ++a) si[a] = *(const float4*)&sc_[(i0 + a) * SPAD + kl];
#pragma unroll
                for (int c = 0; c < 5; ++c) sj[c] = *(const float4*)&sc_[(j0 + c) * SPAD + kl];
#pragma unroll
                for (int a = 0; a < 5; ++a)
#pragma unroll
                    for (int c = 0; c < 5; ++c)
                        acc[a][c] += si[a].x * sj[c].x + si[a].y * sj[c].y +
                                     si[a].z * sj[c].z + si[a].w * sj[c].w;
            }
        }
        if (ch + 1 < 8) WRITEC((ch + 1) & 1);   // vmcnt wait auto-inserted; loads long in flight
        if (ch + 2 < 8) LOADC(ch + 2);          // issue next-next chunk, stays in flight across barrier
        asm volatile("s_waitcnt lgkmcnt(0)" ::: "memory");
        __builtin_amdgcn_s_barrier();           // raw: no vmcnt drain
    }

    if (t < 120) {
#pragma unroll
        for (int a = 0; a < 5; ++a)
#pragma unroll
            for (int c = 0; c < 5; ++c)
                kpart[sk][(i0 + a) * NS + (j0 + c)] = acc[a][c];
    }
    __syncthreads();

    // reduce 8 partials -> M (mirror lower triangle) + lambda I
    for (int item = t; item < NS * NS; item += 256) {
        const int i = item / NS, j = item % NS;
        const int ii = min(i, j), jj = max(i, j);
        float s = 0.f;
#pragma unroll
        for (int p = 0; p < 8; ++p) s += kpart[p][ii * NS + jj];
        if (i == j) s += 1.0f;   // LAMBDA_REG
        M[i * 33 + j] = s;
    }
    if (t < NS * NW) {
        const int i = t / NW, c = t % NW;
        M[i * 33 + NS + c] = (labels[b * NS + i] == c) ? 1.f : 0.f;
    }
    __syncthreads();

    // Gauss-Jordan (K is SPD, diag-dominant)
    for (int p = 0; p < NS; ++p) {
        if (t < 30) prow[t] = M[p * 33 + t];
        if (t >= 32 && t < 32 + NS) pcol[t - 32] = M[(t - 32) * 33 + p];
        __syncthreads();
        const float finv = 1.0f / prow[p];
        for (int item = t; item < NS * 30; item += 256) {
            const int rr = item / 30, cc = item % 30;
            if (rr == p) M[rr * 33 + cc] = prow[cc] * finv;
            else         M[rr * 33 + cc] = M[rr * 33 + cc] - pcol[rr] * finv * prow[cc];
        }
        __syncthreads();
    }

    if (t < NS * NW)
        A_ws[(size_t)b * NS * NW + t] = M[(t / NW) * 33 + NS + (t % NW)];
}

// ---------------- Kernel 2: W = S^T A (LDS), logits = scale * (Q W) ----------------
// 320 threads (5 waves). Q streamed via global_load_lds double-buffered 5-row tiles,
// counted vmcnt + raw barriers (no drain in loop).
__global__ __launch_bounds__(320) void k_logits(const float* __restrict__ Q,
                                                const float* __restrict__ S,
                                                const float* __restrict__ A_ws,
                                                const float* __restrict__ scale,
                                                float* __restrict__ out) {
    const int b = blockIdx.x;
    const int t = threadIdx.x;
    const int wbase = t & ~63;         // wave-uniform lane-0 thread index
    const int l = t & 63;
    const int w = t >> 6;              // wave 0..4

    __shared__ float4 qt[2][1280];     // 40 KB Q tile dbuf; also aliased for S chunks in W-build
    __shared__ float  Wl[NW * 1024];   // 20 KB
    __shared__ float  A_s[128];
    __shared__ float  outbuf[NQ * NW];
    __shared__ float  scsh;

    float* qtf = (float*)qt;
    const float4* Sb4 = (const float4*)(S + (size_t)b * NS * D);
    const float4* Qb4 = (const float4*)(Q + (size_t)b * NQ * D);

    if (t < NS * NW) A_s[t] = A_ws[(size_t)b * NS * NW + t];
    if (t == 0) scsh = scale[0];
    __syncthreads();   // full drain once: A_s/scale visible, vmcnt queue clean

    // ---- W-build: 8 chunks of 128 k, DMA double-buffered ----
    // S chunk buf bb lives at qtf + bb*3840 floats (960 float4 incl. overrun pad)
    auto dma_s = [&](int ch, int bb) {
#pragma unroll
        for (int it = 0; it < 3; ++it) {
            int g = it * 320 + t;                 // 0..959, valid < 800
            int gc = (g < 800) ? g : 799;         // clamp src; overrun lands in pad
            const float* src = (const float*)&Sb4[(gc >> 5) * 256 + ch * 32 + (gc & 31)];
            float* dst = qtf + bb * 3840 + (it * 320 + wbase) * 4;   // wave base
            async_ld16(src, dst);
        }
    };

    dma_s(0, 0); dma_s(1, 1);                     // 6 outstanding per wave
    for (int ch = 0; ch < 8; ++ch) {
        if (ch < 7) asm volatile("s_waitcnt vmcnt(3)" ::: "memory");
        else        asm volatile("s_waitcnt vmcnt(0)" ::: "memory");
        __builtin_amdgcn_s_barrier();             // chunk ch fully in LDS for all waves
        const float* sc_ = qtf + (ch & 1) * 3840;
#pragma unroll
        for (int it = 0; it < 2; ++it) {
            const int item = it * 320 + t;        // 0..639
            const int c = item >> 7, kl = item & 127;
            float sum = 0.f;
#pragma unroll
            for (int j = 0; j < NS; ++j) sum += A_s[j * NW + c] * sc_[j * 128 + kl];
            Wl[c * 1024 + ch * 128 + kl] = sum;
        }
        asm volatile("s_waitcnt lgkmcnt(0)" ::: "memory");
        __builtin_amdgcn_s_barrier();             // all waves done reading buf (ch&1)
        if (ch + 2 < 8) dma_s(ch + 2, ch & 1);
    }

    // ---- Q-phase: 15 tiles x 5 rows, wave w owns row w of each tile ----
    auto dma_q = [&](int tp, int bb) {
#pragma unroll
        for (int it = 0; it < 4; ++it) {
            int g = it * 320 + t;                 // 0..1279 exact
            const float* src = (const float*)&Qb4[(tp * 5 + (g >> 8)) * 256 + (g & 255)];
            float* dst = (float*)qt[bb] + (it * 320 + wbase) * 4;
            async_ld16(src, dst);
        }
    };

    dma_q(0, 0); dma_q(1, 1);                     // 8 outstanding per wave
    const float4* WL4 = (const float4*)Wl;
    const float4* W0 = WL4, *W1 = WL4 + 256, *W2 = WL4 + 512, *W3 = WL4 + 768, *W4 = WL4 + 1024;

    for (int tp = 0; tp < 15; ++tp) {
        if (tp < 14) asm volatile("s_waitcnt vmcnt(4)" ::: "memory");
        else         asm volatile("s_waitcnt vmcnt(0)" ::: "memory");
        __builtin_amdgcn_s_barrier();             // tile tp resident
        const float4* qr = qt[tp & 1] + w * 256;  // my row, 256 float4
        float a0 = 0.f, a1 = 0.f, a2 = 0.f, a3 = 0.f, a4 = 0.f;
#pragma unroll
        for (int i = 0; i < 4; ++i) {
            const int o = i * 64 + l;             // lanes contiguous: 1KB per instruction
            const float4 qv = qr[o];
            const float4 w0 = W0[o], w1 = W1[o], w2 = W2[o], w3 = W3[o], w4 = W4[o];
            a0 += qv.x * w0.x + qv.y * w0.y + qv.z * w0.z + qv.w * w0.w;
            a1 += qv.x * w1.x + qv.y * w1.y + qv.z * w1.z + qv.w * w1.w;
            a2 += qv.x * w2.x + qv.y * w2.y + qv.z * w2.z + qv.w * w2.w;
            a3 += qv.x * w3.x + qv.y * w3.y + qv.z * w3.z + qv.w * w3.w;
            a4 += qv.x * w4.x + qv.y * w4.y + qv.z * w4.z + qv.w * w4.w;
        }
#pragma unroll
        for (int m = 32; m >= 1; m >>= 1) {
            a0 += __shfl_xor(a0, m);
            a1 += __shfl_xor(a1, m);
            a2 += __shfl_xor(a2, m);
            a3 += __shfl_xor(a3, m);
            a4 += __shfl_xor(a4, m);
        }
        if (l == 0) {
            const int r = tp * 5 + w;
            outbuf[r * NW + 0] = a0; outbuf[r * NW + 1] = a1; outbuf[r * NW + 2] = a2;
            outbuf[r * NW + 3] = a3; outbuf[r * NW + 4] = a4;
        }
        __builtin_amdgcn_s_barrier();             // all waves done reading qt[tp&1]
        if (tp + 2 < 15) dma_q(tp + 2, tp & 1);
    }

    __syncthreads();                              // full drain: outbuf visible
    const float scv = scsh;
    for (int i = t; i < NQ * NW; i += 320)
        out[(size_t)b * NQ * NW + i] = outbuf[i] * scv;
}

extern "C" void kernel_launch(void* const* d_in, const int* in_sizes, int n_in,
                              void* d_out, int out_size, void* d_ws, size_t ws_size,
                              hipStream_t stream) {
    const float* Q      = (const float*)d_in[0];
    const float* S      = (const float*)d_in[1];
    const int*   labels = (const int*)d_in[2];
    const float* scale  = (const float*)d_in[3];
    const int B = in_sizes[1] / (NS * D);   // 512

    float* A_ws = (float*)d_ws;             // B*125 floats

    k_solve<<<B, 256, 0, stream>>>(S, labels, A_ws);
    k_logits<<<B, 320, 0, stream>>>(Q, S, A_ws, scale, (float*)d_out);
}

// Round 4
// 285.931 us; speedup vs baseline: 1.0872x; 1.0601x over previous
//
#include <hip/hip_runtime.h>
#include <hip/hip_bf16.h>

#define NS 25      // n_support
#define NW 5       // n_way
#define D  1024
#define NQ 75      // n_query
#define SPAD 132   // k_solve chunk row stride (floats): 132%32=4 -> banks spread per row

// DPP cross-lane add (VALU pipe, no LDS): x += dpp_move(x, ctrl) with 0-fill.
#define DPP_ADD(x, CTRL, RM) do {                                              \
    int _s = __builtin_amdgcn_update_dpp(0, __builtin_bit_cast(int, (x)),      \
                                         (CTRL), (RM), 0xF, true);             \
    (x) += __builtin_bit_cast(float, _s); } while (0)
// full 64-lane sum -> lane 63. rows: shr1,2,4,8 then bcast15 (rows1,3), bcast31 (row3)
#define RED64(x) do {                                                          \
    DPP_ADD(x, 0x111, 0xF); DPP_ADD(x, 0x112, 0xF);                            \
    DPP_ADD(x, 0x114, 0xF); DPP_ADD(x, 0x118, 0xF);                            \
    DPP_ADD(x, 0x142, 0xA); DPP_ADD(x, 0x143, 0x8); } while (0)

// ---------------- Kernel 1: K = S S^T + I, Gauss-Jordan, A = K^{-1} Y ----------------
__global__ __launch_bounds__(256) void k_solve(const float* __restrict__ S,
                                               const int* __restrict__ labels,
                                               float* __restrict__ A_ws) {
    const int b = blockIdx.x;
    const int t = threadIdx.x;

    __shared__ float s_chunk[2][NS * SPAD];   // 2 x 13.2 KB
    __shared__ float kpart[8][NS * NS];       // 20 KB
    __shared__ float M[NS * 33];
    __shared__ float prow[32];
    __shared__ float pcol[NS];

    const float4* Sb4 = (const float4*)(S + (size_t)b * NS * D);

    float4 r0, r1, r2, r3 = make_float4(0.f, 0.f, 0.f, 0.f);
    auto LOADC = [&](int ch) {
        r0 = Sb4[((t      ) >> 5) * 256 + ch * 32 + ((t      ) & 31)];
        r1 = Sb4[((t + 256) >> 5) * 256 + ch * 32 + ((t + 256) & 31)];
        r2 = Sb4[((t + 512) >> 5) * 256 + ch * 32 + ((t + 512) & 31)];
        if (t < 32) r3 = Sb4[((t + 768) >> 5) * 256 + ch * 32 + ((t + 768) & 31)];
    };
    auto WRITEC = [&](int bb) {
        *(float4*)&s_chunk[bb][((t      ) >> 5) * SPAD + ((t      ) & 31) * 4] = r0;
        *(float4*)&s_chunk[bb][((t + 256) >> 5) * SPAD + ((t + 256) & 31) * 4] = r1;
        *(float4*)&s_chunk[bb][((t + 512) >> 5) * SPAD + ((t + 512) & 31) * 4] = r2;
        if (t < 32)
            *(float4*)&s_chunk[bb][((t + 768) >> 5) * SPAD + ((t + 768) & 31) * 4] = r3;
    };

    const int tile = t >> 3;
    const int sk   = t & 7;
    const int ti = (tile < 5) ? 0 : (tile < 9) ? 1 : (tile < 12) ? 2 : (tile < 14) ? 3 : 4;
    const int tbase = (ti == 0) ? 0 : (ti == 1) ? 5 : (ti == 2) ? 9 : (ti == 3) ? 12 : 14;
    const int tj = ti + (tile - tbase);
    const int i0 = ti * 5, j0 = tj * 5;
    float acc[5][5] = {};

    LOADC(0); WRITEC(0); LOADC(1);
    asm volatile("s_waitcnt lgkmcnt(0)" ::: "memory");
    __builtin_amdgcn_s_barrier();

    for (int ch = 0; ch < 8; ++ch) {
        if (t < 120) {
            const float* sc_ = s_chunk[ch & 1];
#pragma unroll
            for (int ii = 0; ii < 4; ++ii) {
                const int kl = sk * 4 + ii * 32;
                float4 si[5], sj[5];
#pragma unroll
                for (int a = 0; a < 5; ++a) si[a] = *(const float4*)&sc_[(i0 + a) * SPAD + kl];
#pragma unroll
                for (int c = 0; c < 5; ++c) sj[c] = *(const float4*)&sc_[(j0 + c) * SPAD + kl];
#pragma unroll
                for (int a = 0; a < 5; ++a)
#pragma unroll
                    for (int c = 0; c < 5; ++c)
                        acc[a][c] += si[a].x * sj[c].x + si[a].y * sj[c].y +
                                     si[a].z * sj[c].z + si[a].w * sj[c].w;
            }
        }
        if (ch + 1 < 8) WRITEC((ch + 1) & 1);
        if (ch + 2 < 8) LOADC(ch + 2);
        asm volatile("s_waitcnt lgkmcnt(0)" ::: "memory");
        __builtin_amdgcn_s_barrier();
    }

    if (t < 120) {
#pragma unroll
        for (int a = 0; a < 5; ++a)
#pragma unroll
            for (int c = 0; c < 5; ++c)
                kpart[sk][(i0 + a) * NS + (j0 + c)] = acc[a][c];
    }
    __syncthreads();

    for (int item = t; item < NS * NS; item += 256) {
        const int i = item / NS, j = item % NS;
        const int ii = min(i, j), jj = max(i, j);
        float s = 0.f;
#pragma unroll
        for (int p = 0; p < 8; ++p) s += kpart[p][ii * NS + jj];
        if (i == j) s += 1.0f;   // LAMBDA_REG
        M[i * 33 + j] = s;
    }
    if (t < NS * NW) {
        const int i = t / NW, c = t % NW;
        M[i * 33 + NS + c] = (labels[b * NS + i] == c) ? 1.f : 0.f;
    }
    __syncthreads();

    for (int p = 0; p < NS; ++p) {
        if (t < 30) prow[t] = M[p * 33 + t];
        if (t >= 32 && t < 32 + NS) pcol[t - 32] = M[(t - 32) * 33 + p];
        __syncthreads();
        const float finv = 1.0f / prow[p];
        for (int item = t; item < NS * 30; item += 256) {
            const int rr = item / 30, cc = item % 30;
            if (rr == p) M[rr * 33 + cc] = prow[cc] * finv;
            else         M[rr * 33 + cc] = M[rr * 33 + cc] - pcol[rr] * finv * prow[cc];
        }
        __syncthreads();
    }

    if (t < NS * NW)
        A_ws[(size_t)b * NS * NW + t] = M[(t / NW) * 33 + NS + (t % NW)];
}

// ---------------- Kernel 2: W in registers, Q global->reg stream, DPP reduce ----------------
// 512 threads (8 waves). Wave w owns q-rows {w, w+8, ...}. Lane l owns k-float4
// {l+64s : s=0..3} of all 5 W columns (80 VGPR). Per row: 4 coalesced 1KB global
// loads (depth-3 ring) + 80 FMA + 6-step DPP reduce (VALU, zero LDS).
__global__ __launch_bounds__(512, 3) void k_logits(const float* __restrict__ Q,
                                                   const float* __restrict__ S,
                                                   const float* __restrict__ A_ws,
                                                   const float* __restrict__ scale,
                                                   float* __restrict__ out) {
    const int b = blockIdx.x;
    const int t = threadIdx.x;
    const int l = t & 63;
    const int w = t >> 6;

    __shared__ float4 Wsh4[NW * 256];     // 20 KB
    __shared__ float  A_s[NS * NW];
    __shared__ float  outbuf[NQ * NW];
    __shared__ float  scsh;

    if (t < NS * NW) A_s[t] = A_ws[(size_t)b * NS * NW + t];
    if (t == 0) scsh = scale[0];
    __syncthreads();

    // ---- W-build: thread t<256 owns float4-column t; W[c][k] = sum_j A[j][c] S[j][k]
    if (t < 256) {
        const float4* S4 = (const float4*)(S + (size_t)b * NS * D);
        float4 wa0 = {0,0,0,0}, wa1 = {0,0,0,0}, wa2 = {0,0,0,0}, wa3 = {0,0,0,0}, wa4 = {0,0,0,0};
#pragma unroll
        for (int j = 0; j < NS; ++j) {
            const float4 sv = S4[j * 256 + t];
            const float a0 = A_s[j * NW + 0], a1 = A_s[j * NW + 1], a2 = A_s[j * NW + 2];
            const float a3 = A_s[j * NW + 3], a4 = A_s[j * NW + 4];
            wa0.x += a0 * sv.x; wa0.y += a0 * sv.y; wa0.z += a0 * sv.z; wa0.w += a0 * sv.w;
            wa1.x += a1 * sv.x; wa1.y += a1 * sv.y; wa1.z += a1 * sv.z; wa1.w += a1 * sv.w;
            wa2.x += a2 * sv.x; wa2.y += a2 * sv.y; wa2.z += a2 * sv.z; wa2.w += a2 * sv.w;
            wa3.x += a3 * sv.x; wa3.y += a3 * sv.y; wa3.z += a3 * sv.z; wa3.w += a3 * sv.w;
            wa4.x += a4 * sv.x; wa4.y += a4 * sv.y; wa4.z += a4 * sv.z; wa4.w += a4 * sv.w;
        }
        Wsh4[0 * 256 + t] = wa0; Wsh4[1 * 256 + t] = wa1; Wsh4[2 * 256 + t] = wa2;
        Wsh4[3 * 256 + t] = wa3; Wsh4[4 * 256 + t] = wa4;
    }
    __syncthreads();

    // ---- load W fragments to registers: 20 ds_read_b128, conflict-free
    float4 W4[NW][4];
#pragma unroll
    for (int c = 0; c < NW; ++c)
#pragma unroll
        for (int s = 0; s < 4; ++s)
            W4[c][s] = Wsh4[c * 256 + l + 64 * s];

    // ---- Q-phase: software-pipelined rows, depth-3 register ring
    const float4* Qb4 = (const float4*)(Q + (size_t)b * NQ * D);
    float4 qA[4], qB[4], qC[4];

    auto ISSUE = [&](float4* qv, int i) {        // load row (w + 8i), clamped
        int rr = w + 8 * i; if (rr > 74) rr -= 8;
        const float4* p = Qb4 + rr * 256 + l;
        qv[0] = p[0]; qv[1] = p[64]; qv[2] = p[128]; qv[3] = p[192];
    };
    auto BODY = [&](const float4* qv, int i) {   // dot row with 5 W cols, reduce, store
        float a0 = 0.f, a1 = 0.f, a2 = 0.f, a3 = 0.f, a4 = 0.f;
#pragma unroll
        for (int s = 0; s < 4; ++s) {
            const float4 q = qv[s];
            a0 += q.x * W4[0][s].x + q.y * W4[0][s].y + q.z * W4[0][s].z + q.w * W4[0][s].w;
            a1 += q.x * W4[1][s].x + q.y * W4[1][s].y + q.z * W4[1][s].z + q.w * W4[1][s].w;
            a2 += q.x * W4[2][s].x + q.y * W4[2][s].y + q.z * W4[2][s].z + q.w * W4[2][s].w;
            a3 += q.x * W4[3][s].x + q.y * W4[3][s].y + q.z * W4[3][s].z + q.w * W4[3][s].w;
            a4 += q.x * W4[4][s].x + q.y * W4[4][s].y + q.z * W4[4][s].z + q.w * W4[4][s].w;
        }
        RED64(a0); RED64(a1); RED64(a2); RED64(a3); RED64(a4);
        if (l == 63) {
            int rr = w + 8 * i; if (rr > 74) rr -= 8;
            outbuf[rr * NW + 0] = a0; outbuf[rr * NW + 1] = a1; outbuf[rr * NW + 2] = a2;
            outbuf[rr * NW + 3] = a3; outbuf[rr * NW + 4] = a4;
        }
    };
#define WAITV(N) asm volatile("s_waitcnt vmcnt(" #N ")" ::: "memory")

    ISSUE(qA, 0); ISSUE(qB, 1); ISSUE(qC, 2);
    WAITV(8);  BODY(qA, 0); ISSUE(qA, 3);
    WAITV(8);  BODY(qB, 1); ISSUE(qB, 4);
    WAITV(8);  BODY(qC, 2); ISSUE(qC, 5);
    WAITV(8);  BODY(qA, 3); ISSUE(qA, 6);
    WAITV(8);  BODY(qB, 4); ISSUE(qB, 7);
    WAITV(8);  BODY(qC, 5); ISSUE(qC, 8);
    WAITV(8);  BODY(qA, 6); ISSUE(qA, 9);
    WAITV(8);  BODY(qB, 7);
    WAITV(4);  BODY(qC, 8);
    WAITV(0);  BODY(qA, 9);   // rows 75..79 clamp to the wave's previous row (benign rewrite)

    __syncthreads();
    const float scv = scsh;
    for (int i = t; i < NQ * NW; i += 512)
        out[(size_t)b * NQ * NW + i] = outbuf[i] * scv;
}

extern "C" void kernel_launch(void* const* d_in, const int* in_sizes, int n_in,
                              void* d_out, int out_size, void* d_ws, size_t ws_size,
                              hipStream_t stream) {
    const float* Q      = (const float*)d_in[0];
    const float* S      = (const float*)d_in[1];
    const int*   labels = (const int*)d_in[2];
    const float* scale  = (const float*)d_in[3];
    const int B = in_sizes[1] / (NS * D);   // 512

    float* A_ws = (float*)d_ws;             // B*125 floats

    k_solve<<<B, 256, 0, stream>>>(S, labels, A_ws);
    k_logits<<<B, 512, 0, stream>>>(Q, S, A_ws, scale, (float*)d_out);
}